// Round 9
// baseline (148.740 us; speedup 1.0000x reference)
//
#include <hip/hip_runtime.h>
#include <stdint.h>

// Problem constants (static per reference)
#define NG    256    // graphs
#define NPG   128    // nodes per graph
#define PP    8      // perturbations
#define IND   64     // input dim
#define HID   128    // hidden
#define OUTD  10     // classes

typedef short bf16x8 __attribute__((ext_vector_type(8)));
typedef float f32x4  __attribute__((ext_vector_type(4)));

// RNE f32->bf16 (bit trick) — the verified-correct conversion on this path.
static __device__ __forceinline__ unsigned short f2bf(float f) {
    unsigned int u = __float_as_uint(f);
    u += 0x7FFFu + ((u >> 16) & 1u);
    return (unsigned short)(u >> 16);
}

static __device__ __forceinline__ f32x4 mfma16(bf16x8 a, bf16x8 b, f32x4 c) {
    return __builtin_amdgcn_mfma_f32_16x16x32_bf16(a, b, c, 0, 0, 0);
}

// ws layout (shorts) — weights only:
//   [0)      W1t  128x64   (Wt[out][in])
//   [8192)   W2t  128x128
//   [24576)  Wg1t 128x128
//   [40960)  Wg2t 128x128
//   [57344)  Wb1t 128x128
//   [73728)  Wb2t 128x128

#define LSTR 136   // bf16 LDS row stride for 128-col tiles (272 B): 68 words
                   // == 4 mod 32 -> only 2-way bank aliasing (free)
#define XBS  72    // x-slab stride (64 cols + pad): 36 words == 4 mod 32, same
#define SSTR 132   // f32 scratch stride: 132 words == 4 mod 32, same property

// ---------------------------------------------------------------------------
// Kernel 0: convert + transpose weights (coalesced writes; src stays in L2)
// ---------------------------------------------------------------------------
__global__ void prep_weights(const float* __restrict__ Wl1, const float* __restrict__ Wl2,
                             const float* __restrict__ Wg1, const float* __restrict__ Wg2,
                             const float* __restrict__ Wb1, const float* __restrict__ Wb2,
                             unsigned short* __restrict__ ws) {
    int e = blockIdx.x * blockDim.x + threadIdx.x;
    if (e < 8192) {
        int n = e >> 6, k = e & 63;
        ws[e] = f2bf(Wl1[k * HID + n]);
        return;
    }
    int e2 = e - 8192;
    int m = e2 >> 14;
    int idx = e2 & 16383;
    int n = idx >> 7, k = idx & 127;
    const float* src;
    if      (m == 0) src = Wl2;
    else if (m == 1) src = Wg1;
    else if (m == 2) src = Wg2;
    else if (m == 3) src = Wb1;
    else             src = Wb2;
    ws[8192 + m * 16384 + idx] = f2bf(src[k * HID + n]);
}

// ---------------------------------------------------------------------------
// Fused kernel: ONE BLOCK PER GRAPH, 512 threads = 8 waves (round-6 schedule,
// which outperformed the round-7/8 variants).
// Round-9 change: rounds 7/8 proved the kernel is LDS-BANDWIDTH-bound (dur
// identical 42 us at 2x occupancy; bank-conflict cycles ~19% of budget; each
// wave read ALL of h1/xb = 8x amplification). New wave->work mapping:
//   wave = (c, h): c = wave&3 owns 32 output cols (2 weight frags, each LDS
//   read feeds 2 MFMAs); h = wave>>2 owns the 64 rows of perturbations
//   p = 4h..4h+3.
// Halves b128 read traffic in L1 (128->64/tile), L2 (256->128/tile) and
// phase B (256->128/layer); MFMA count unchanged. The perturbation-sum now
// needs an h-combine: h=1 stores its f32 partial to an 8.4 KB scratch, h=0
// adds its own partial next iteration (barrier-separated) and writes bf16
// agg. Pool partials per h are summed in the decoder. Two f32 sums are
// reassociated vs round-6 (ulp-level; threshold has 2.7x headroom).
// Barriers: 2/tile, unchanged. LDS 116288 B -> 1 block/CU (LDS-bound anyway).
// ---------------------------------------------------------------------------
__global__ __launch_bounds__(512) void graph_fused(
    const float* __restrict__ x,
    const unsigned short* __restrict__ wt,
    const float* __restrict__ bl1, const float* __restrict__ bl2,
    const float* __restrict__ bg1, const float* __restrict__ bg2,
    const float* __restrict__ bb1, const float* __restrict__ bb2,
    const float* __restrict__ Wd1, const float* __restrict__ bd1,
    const float* __restrict__ Wd2, const float* __restrict__ bd2,
    float* __restrict__ out)
{
    // LDS map (bytes):
    //   [0)      xb0  128*XBS shorts (18432)
    //   [18432)  xb1  128*XBS shorts (18432)
    //   [36864)  h1   128*LSTR shorts (34816)   } phase-B ping-pong
    //   [71680)  aggL 128*LSTR shorts (34816)   }
    //   [106496) scrF 16*SSTR f32 (8448)  h=1 agg partials
    //   [114944) pool 2*128 f32 (1024)
    //   [115968) z    64 f32 (256)
    //   [116224) zz   16 f32 (64)
    __shared__ __align__(16) unsigned char smem[116288];
    unsigned short* xb0  = (unsigned short*)(smem);
    unsigned short* xb1  = (unsigned short*)(smem + 18432);
    unsigned short* h1   = (unsigned short*)(smem + 36864);
    unsigned short* aggL = (unsigned short*)(smem + 71680);
    float* scrF = (float*)(smem + 106496);
    float* pool = (float*)(smem + 114944);
    float* z    = (float*)(smem + 115968);
    float* zz   = (float*)(smem + 116224);

    const int g    = blockIdx.x;
    const int tid  = threadIdx.x;
    const int wave = tid >> 6;      // 0..7
    const int c    = wave & 3;      // out-col group: cols [32c, 32c+32)
    const int h    = wave >> 2;     // perturbation half: p in [4h, 4h+4)
    const int lane = tid & 63;
    const int q    = lane >> 4;
    const int r    = lane & 15;
    const int oc   = c * 32;

    const float* xg = x + (size_t)g * (NPG * PP) * IND;

    // ---- per-thread staging geometry: 8192 elems/tile, 16 per thread ----
    int sIt[4], cIt[4], gRow[4];
#pragma unroll
    for (int it = 0; it < 4; ++it) {
        int e = it * 2048 + tid * 4;       // element index in the tile slab
        int s = e >> 6;                    // LDS row (p*16 + rr)
        sIt[it]  = s;
        cIt[it]  = e & 63;
        gRow[it] = (s >> 4) * 128 + (s & 15);   // global row sans tile*16
    }
    float4 ld[4];

#define ISSUE(T)                                                              \
    do {                                                                      \
        _Pragma("unroll")                                                     \
        for (int it = 0; it < 4; ++it)                                        \
            ld[it] = *(const float4*)(xg + (size_t)(gRow[it] + (T) * 16) * IND + cIt[it]); \
    } while (0)

#define XWRITE(dst)                                                           \
    do {                                                                      \
        _Pragma("unroll")                                                     \
        for (int it = 0; it < 4; ++it) {                                      \
            ushort4 w4;                                                       \
            w4.x = f2bf(ld[it].x); w4.y = f2bf(ld[it].y);                     \
            w4.z = f2bf(ld[it].z); w4.w = f2bf(ld[it].w);                     \
            *(ushort4*)(&(dst)[sIt[it] * XBS + cIt[it]]) = w4;                \
        }                                                                     \
    } while (0)

    // ---- weight fragments: this wave's 32 out-cols (2 frag sets) ----
    bf16x8 w1f[2][2];
#pragma unroll
    for (int t = 0; t < 2; ++t)
#pragma unroll
        for (int ks = 0; ks < 2; ++ks)
            w1f[t][ks] = *(const bf16x8*)(wt + (oc + t * 16 + r) * 64 + ks * 32 + q * 8);

    const unsigned short* w2t = wt + 8192;
    bf16x8 w2f[2][4];
#pragma unroll
    for (int t = 0; t < 2; ++t)
#pragma unroll
        for (int ks = 0; ks < 4; ++ks)
            w2f[t][ks] = *(const bf16x8*)(w2t + (oc + t * 16 + r) * 128 + ks * 32 + q * 8);

    float4 b1s[2], b2s[2];
#pragma unroll
    for (int t = 0; t < 2; ++t) {
        b1s[t] = *(const float4*)(bl1 + oc + t * 16 + q * 4);
        b2s[t] = *(const float4*)(bl2 + oc + t * 16 + q * 4);
    }

    // ---- prologue: tile 0 staged, tile 1 in flight ----
    ISSUE(0);
    XWRITE(xb0);
    ISSUE(1);
    __syncthreads();

    // ======================= phase A: 8 node-tiles =========================
    f32x4 aPrev0, aPrev1;    // h=0's agg partial carried to the next iteration

    for (int nt = 0; nt < 8; ++nt) {
        unsigned short* xcur = (nt & 1) ? xb1 : xb0;

        // combine previous tile's agg (h=0): scrF written pre-b2(nt-1);
        // h=1's next scrF write is after b1(nt), our reads precede our b1
        // arrival -> race-free. aggL untouched by concurrent L1.
        if (nt > 0 && h == 0) {
            float4 s0 = *(const float4*)(&scrF[r * SSTR + oc + q * 4]);
            float4 s1 = *(const float4*)(&scrF[r * SSTR + oc + 16 + q * 4]);
            ushort4 v0, v1;
            v0.x = f2bf(aPrev0[0] + s0.x);
            v0.y = f2bf(aPrev0[1] + s0.y);
            v0.z = f2bf(aPrev0[2] + s0.z);
            v0.w = f2bf(aPrev0[3] + s0.w);
            v1.x = f2bf(aPrev1[0] + s1.x);
            v1.y = f2bf(aPrev1[1] + s1.y);
            v1.z = f2bf(aPrev1[2] + s1.z);
            v1.w = f2bf(aPrev1[3] + s1.w);
            *(ushort4*)(&aggL[((nt - 1) * 16 + r) * LSTR + oc + q * 4]) = v0;
            *(ushort4*)(&aggL[((nt - 1) * 16 + r) * LSTR + oc + 16 + q * 4]) = v1;
        }

        // ---- layer 1 (K=64): this wave's 4 perturbations, 32 out-cols ----
#pragma unroll
        for (int pp = 0; pp < 4; ++pp) {
            const int p = h * 4 + pp;
            f32x4 a0 = (f32x4){0.f, 0.f, 0.f, 0.f};
            f32x4 a1 = (f32x4){0.f, 0.f, 0.f, 0.f};
#pragma unroll
            for (int ks = 0; ks < 2; ++ks) {
                bf16x8 xf = *(const bf16x8*)(&xcur[(p * 16 + r) * XBS + ks * 32 + q * 8]);
                a0 = mfma16(w1f[0][ks], xf, a0);
                a1 = mfma16(w1f[1][ks], xf, a1);
            }
            ushort4 v0, v1;
            v0.x = f2bf(fmaxf(a0[0] + b1s[0].x, 0.f));
            v0.y = f2bf(fmaxf(a0[1] + b1s[0].y, 0.f));
            v0.z = f2bf(fmaxf(a0[2] + b1s[0].z, 0.f));
            v0.w = f2bf(fmaxf(a0[3] + b1s[0].w, 0.f));
            v1.x = f2bf(fmaxf(a1[0] + b1s[1].x, 0.f));
            v1.y = f2bf(fmaxf(a1[1] + b1s[1].y, 0.f));
            v1.z = f2bf(fmaxf(a1[2] + b1s[1].z, 0.f));
            v1.w = f2bf(fmaxf(a1[3] + b1s[1].w, 0.f));
            *(ushort4*)(&h1[(p * 16 + r) * LSTR + oc + q * 4]) = v0;
            *(ushort4*)(&h1[(p * 16 + r) * LSTR + oc + 16 + q * 4]) = v1;
        }

        // stage next tile's x + refill regs two tiles ahead (round-6 pattern)
        if (nt < 7) {
            if (nt & 1) XWRITE(xb0); else XWRITE(xb1);
        }
        if (nt < 6) ISSUE(nt + 2);

        __syncthreads();   // b1: h1 complete; next-x staged

        // ---- layer 2 (K=128): relu-accumulate this wave's 4 p's ----
        f32x4 g0 = (f32x4){0.f, 0.f, 0.f, 0.f};
        f32x4 g1 = (f32x4){0.f, 0.f, 0.f, 0.f};
#pragma unroll
        for (int pp = 0; pp < 4; ++pp) {
            const int p = h * 4 + pp;
            f32x4 c0 = (f32x4){0.f, 0.f, 0.f, 0.f};
            f32x4 c1 = (f32x4){0.f, 0.f, 0.f, 0.f};
#pragma unroll
            for (int ks = 0; ks < 4; ++ks) {
                bf16x8 hf = *(const bf16x8*)(&h1[(p * 16 + r) * LSTR + ks * 32 + q * 8]);
                c0 = mfma16(w2f[0][ks], hf, c0);
                c1 = mfma16(w2f[1][ks], hf, c1);
            }
            g0[0] += fmaxf(c0[0] + b2s[0].x, 0.f);
            g0[1] += fmaxf(c0[1] + b2s[0].y, 0.f);
            g0[2] += fmaxf(c0[2] + b2s[0].z, 0.f);
            g0[3] += fmaxf(c0[3] + b2s[0].w, 0.f);
            g1[0] += fmaxf(c1[0] + b2s[1].x, 0.f);
            g1[1] += fmaxf(c1[1] + b2s[1].y, 0.f);
            g1[2] += fmaxf(c1[2] + b2s[1].z, 0.f);
            g1[3] += fmaxf(c1[3] + b2s[1].w, 0.f);
        }
        if (h == 1) {
            float4 f0, f1;
            f0.x = g0[0]; f0.y = g0[1]; f0.z = g0[2]; f0.w = g0[3];
            f1.x = g1[0]; f1.y = g1[1]; f1.z = g1[2]; f1.w = g1[3];
            *(float4*)(&scrF[r * SSTR + oc + q * 4]) = f0;
            *(float4*)(&scrF[r * SSTR + oc + 16 + q * 4]) = f1;
        } else {
            aPrev0 = g0;
            aPrev1 = g1;
        }

        __syncthreads();   // b2: h1 rewritable; scrF ready for combine
    }

    // final tile's combine (h=0), then gate phase B on aggL completeness
    if (h == 0) {
        float4 s0 = *(const float4*)(&scrF[r * SSTR + oc + q * 4]);
        float4 s1 = *(const float4*)(&scrF[r * SSTR + oc + 16 + q * 4]);
        ushort4 v0, v1;
        v0.x = f2bf(aPrev0[0] + s0.x);
        v0.y = f2bf(aPrev0[1] + s0.y);
        v0.z = f2bf(aPrev0[2] + s0.z);
        v0.w = f2bf(aPrev0[3] + s0.w);
        v1.x = f2bf(aPrev1[0] + s1.x);
        v1.y = f2bf(aPrev1[1] + s1.y);
        v1.z = f2bf(aPrev1[2] + s1.z);
        v1.w = f2bf(aPrev1[3] + s1.w);
        *(ushort4*)(&aggL[(7 * 16 + r) * LSTR + oc + q * 4]) = v0;
        *(ushort4*)(&aggL[(7 * 16 + r) * LSTR + oc + 16 + q * 4]) = v1;
    }
    __syncthreads();

    // ================= phase B: 4x (Linear+ReLU) + pool ====================
    // wave (c,h): out cols [32c,32c+32), node rows [64h, 64h+64).
    int cur = 0;
#pragma unroll
    for (int l = 0; l < 4; ++l) {
        const unsigned short* wl = wt + 24576 + l * 16384;
        const float* bl = (l == 0) ? bg1 : (l == 1) ? bg2 : (l == 2) ? bb1 : bb2;

        bf16x8 wf[2][4];
#pragma unroll
        for (int t = 0; t < 2; ++t)
#pragma unroll
            for (int ks = 0; ks < 4; ++ks)
                wf[t][ks] = *(const bf16x8*)(wl + (oc + t * 16 + r) * 128 + ks * 32 + q * 8);

        unsigned short* Xb = cur ? h1 : aggL;
        unsigned short* Yb = cur ? aggL : h1;

        f32x4 acc[2][4];
#pragma unroll
        for (int t = 0; t < 2; ++t)
#pragma unroll
            for (int j = 0; j < 4; ++j)
                acc[t][j] = (f32x4){0.f, 0.f, 0.f, 0.f};

#pragma unroll
        for (int ks = 0; ks < 4; ++ks) {
#pragma unroll
            for (int j = 0; j < 4; ++j) {
                int row = h * 64 + j * 16 + r;
                bf16x8 xf = *(const bf16x8*)(&Xb[row * LSTR + ks * 32 + q * 8]);
                acc[0][j] = mfma16(wf[0][ks], xf, acc[0][j]);
                acc[1][j] = mfma16(wf[1][ks], xf, acc[1][j]);
            }
        }

        if (l < 3) {
#pragma unroll
            for (int t = 0; t < 2; ++t) {
                float4 bs = *(const float4*)(bl + oc + t * 16 + q * 4);
#pragma unroll
                for (int j = 0; j < 4; ++j) {
                    int row = h * 64 + j * 16 + r;
                    ushort4 v;
                    v.x = f2bf(fmaxf(acc[t][j][0] + bs.x, 0.f));
                    v.y = f2bf(fmaxf(acc[t][j][1] + bs.y, 0.f));
                    v.z = f2bf(fmaxf(acc[t][j][2] + bs.z, 0.f));
                    v.w = f2bf(fmaxf(acc[t][j][3] + bs.w, 0.f));
                    *(ushort4*)(&Yb[row * LSTR + oc + t * 16 + q * 4]) = v;
                }
            }
            __syncthreads();
            cur ^= 1;
        } else {
            float s[2][4];
#pragma unroll
            for (int t = 0; t < 2; ++t) {
                float4 bs = *(const float4*)(bl + oc + t * 16 + q * 4);
                s[t][0] = s[t][1] = s[t][2] = s[t][3] = 0.f;
#pragma unroll
                for (int j = 0; j < 4; ++j) {
                    s[t][0] += fmaxf(acc[t][j][0] + bs.x, 0.f);
                    s[t][1] += fmaxf(acc[t][j][1] + bs.y, 0.f);
                    s[t][2] += fmaxf(acc[t][j][2] + bs.z, 0.f);
                    s[t][3] += fmaxf(acc[t][j][3] + bs.w, 0.f);
                }
            }
#pragma unroll
            for (int m = 1; m < 16; m <<= 1) {
#pragma unroll
                for (int t = 0; t < 2; ++t)
#pragma unroll
                    for (int i = 0; i < 4; ++i)
                        s[t][i] += __shfl_xor(s[t][i], m, 64);
            }
            if (r == 0) {
#pragma unroll
                for (int t = 0; t < 2; ++t)
#pragma unroll
                    for (int i = 0; i < 4; ++i)
                        pool[h * 128 + oc + t * 16 + q * 4 + i] = s[t][i];
            }
        }
    }
    __syncthreads();

    // ===================== decoder + log_softmax ===========================
    if (tid < 64) {
        float a0 = bd1[tid], a1 = 0.f, a2 = 0.f, a3 = 0.f;
#pragma unroll
        for (int k = 0; k < 128; k += 4) {
            a0 += (pool[k]     + pool[128 + k])     * Wd1[(k)     * 64 + tid];
            a1 += (pool[k + 1] + pool[128 + k + 1]) * Wd1[(k + 1) * 64 + tid];
            a2 += (pool[k + 2] + pool[128 + k + 2]) * Wd1[(k + 2) * 64 + tid];
            a3 += (pool[k + 3] + pool[128 + k + 3]) * Wd1[(k + 3) * 64 + tid];
        }
        z[tid] = fmaxf((a0 + a1) + (a2 + a3), 0.f);
    }
    __syncthreads();
    if (tid < OUTD) {
        float b0 = bd2[tid], b1 = 0.f;
#pragma unroll
        for (int k = 0; k < 64; k += 2) {
            b0 += z[k]     * Wd2[(k)     * OUTD + tid];
            b1 += z[k + 1] * Wd2[(k + 1) * OUTD + tid];
        }
        zz[tid] = b0 + b1;
    }
    __syncthreads();
    if (tid == 0) {
        float m = -1e30f;
#pragma unroll
        for (int j = 0; j < OUTD; ++j) m = fmaxf(m, zz[j]);
        float ssum = 0.f;
#pragma unroll
        for (int j = 0; j < OUTD; ++j) ssum += expf(zz[j] - m);
        float ls = logf(ssum);
#pragma unroll
        for (int j = 0; j < OUTD; ++j) out[g * OUTD + j] = zz[j] - m - ls;
    }
#undef ISSUE
#undef XWRITE
}

extern "C" void kernel_launch(void* const* d_in, const int* in_sizes, int n_in,
                              void* d_out, int out_size, void* d_ws, size_t ws_size,
                              hipStream_t stream) {
    const float* x   = (const float*)d_in[0];
    // d_in[1] = ptr (unused; structure is static)
    const float* Wl1 = (const float*)d_in[2];
    const float* bl1 = (const float*)d_in[3];
    const float* Wl2 = (const float*)d_in[4];
    const float* bl2 = (const float*)d_in[5];
    const float* Wg1 = (const float*)d_in[6];
    const float* bg1 = (const float*)d_in[7];
    const float* Wg2 = (const float*)d_in[8];
    const float* bg2 = (const float*)d_in[9];
    const float* Wb1 = (const float*)d_in[10];
    const float* bb1 = (const float*)d_in[11];
    const float* Wb2 = (const float*)d_in[12];
    const float* bb2 = (const float*)d_in[13];
    const float* Wd1 = (const float*)d_in[14];
    const float* bd1 = (const float*)d_in[15];
    const float* Wd2 = (const float*)d_in[16];
    const float* bd2 = (const float*)d_in[17];

    unsigned short* ws = (unsigned short*)d_ws;

    prep_weights<<<352, 256, 0, stream>>>(Wl1, Wl2, Wg1, Wg2, Wb1, Wb2, ws);
    graph_fused<<<NG, 512, 0, stream>>>(x, ws, bl1, bl2, bg1, bg2, bb1, bb2,
                                        Wd1, bd1, Wd2, bd2, (float*)d_out);
}